// Round 5
// baseline (224.472 us; speedup 1.0000x reference)
//
#include <hip/hip_runtime.h>

typedef _Float16 f16;
typedef _Float16 v8hf __attribute__((ext_vector_type(8)));
typedef _Float16 v4hf __attribute__((ext_vector_type(4)));
typedef _Float16 v2hf __attribute__((ext_vector_type(2)));
typedef __fp16   v2pk __attribute__((ext_vector_type(2)));
typedef float    v4f  __attribute__((ext_vector_type(4)));

#define NPTS 16384
#define PTS  8              // points per workgroup -> M = 6*PTS = 48 site-rows
#define NLAYER_ELEMS 65536  // 256*256 f16 per layer per split

__device__ __forceinline__ v2hf pkrtz(float a, float b) {
    v2pk r = __builtin_amdgcn_cvt_pkrtz(a, b);
    return __builtin_bit_cast(v2hf, r);
}

// XOR-swizzled LDS index for logical (row m, f16-col j); row stride 256 f16.
// 16B chunks; phys chunk = chunk ^ (m&7). All accesses stay inside one chunk.
__device__ __forceinline__ int swz(int m, int j) {
    return m * 256 + ((((j >> 3) ^ (m & 7)) << 3) | (j & 7));
}

// ---------------- prepass: split+transpose W1..W3 into MFMA A-operand order ----
// Bpack[L][ks][n][kk] (f16). 96 blocks x 256 thr, each thread 8 kk of one n.
__global__ void pack_weights(const float* __restrict__ W1, const float* __restrict__ W2,
                             const float* __restrict__ W3, f16* __restrict__ bh,
                             f16* __restrict__ bl) {
    const int b  = blockIdx.x;           // b = L*32 + ks*4 + q
    const int q  = b & 3;
    const int ks = (b >> 2) & 7;
    const int L  = b >> 5;
    const float* W = (L == 0) ? W1 : (L == 1) ? W2 : W3;
    const int n   = q * 64 + (threadIdx.x & 63);
    const int kk0 = (threadIdx.x >> 6) * 8;
    f16 h[8], l[8];
    #pragma unroll
    for (int i = 0; i < 8; ++i) {
        float w = W[(ks * 32 + kk0 + i) * 256 + n];   // coalesced along n
        f16 hh = (f16)w;
        h[i] = hh;
        l[i] = (f16)(w - (float)hh);
    }
    size_t off = (size_t)L * NLAYER_ELEMS + (size_t)(ks * 256 + n) * 32 + kk0;
    *(v8hf*)(bh + off) = *(v8hf*)h;
    *(v8hf*)(bl + off) = *(v8hf*)l;
}

__device__ __forceinline__ void store_split(const float* a, int m, int nb,
                                            f16* __restrict__ Ah, f16* __restrict__ Al) {
    v2hf h01 = pkrtz(a[0], a[1]);
    v2hf h23 = pkrtz(a[2], a[3]);
    v2hf l01 = pkrtz(a[0] - (float)h01[0], a[1] - (float)h01[1]);
    v2hf l23 = pkrtz(a[2] - (float)h23[0], a[3] - (float)h23[1]);
    v4hf hi = { h01[0], h01[1], h23[0], h23[1] };
    v4hf lo = { l01[0], l01[1], l23[0], l23[1] };
    int idx = swz(m, nb);
    *(v4hf*)&Ah[idx] = hi;
    *(v4hf*)&Al[idx] = lo;
}

// ---------------- main kernel --------------------------------------------------
// Channels: 0=val 1=dx 2=dy 3=dt 4=dxx 5=dyy; site-row m = c*PTS + p.
// Hidden GEMM computes Z^T via mfma(A-op=W^T frag, B-op=A^T frag):
//   D row (quad*4+reg) = neuron col n, D col (lane&15) = site-row m.
// Fused epilogue+activation: lanes (ln, ln+8) pair-hold all 6 channels of p=ln&7.
__global__ __launch_bounds__(256, 3) void pinn_burgers_kernel(
    const float* __restrict__ gx, const float* __restrict__ gy,
    const float* __restrict__ gt, const float* __restrict__ gnu,
    const float* __restrict__ W0, const float* __restrict__ b0,
    const float* __restrict__ b1, const float* __restrict__ b2,
    const float* __restrict__ b3,
    const float* __restrict__ W4, const float* __restrict__ b4,
    const f16* __restrict__ bh, const f16* __restrict__ bl,
    float* __restrict__ out)
{
    __shared__ f16 Ah[48 * 256];   // 24576 B, swizzled layout
    __shared__ f16 Al[48 * 256];   // 24576 B
    __shared__ float red[PTS][12];
    __shared__ float pin[4][PTS];

    const int tid  = threadIdx.x;
    const int lane = tid & 63;
    const int wv   = tid >> 6;        // 4 waves
    const int ln   = lane & 15;
    const int quad = lane >> 4;
    const int lnx  = ln & 7;
    const int p0   = blockIdx.x * PTS;

    if (tid < 4 * PTS) {
        int c = tid >> 3, p = tid & 7;
        const float* src = (c == 0) ? gx : (c == 1) ? gy : (c == 2) ? gt : gnu;
        pin[c][p] = src[p0 + p];
    }
    __syncthreads();

    // ---------------- layer 0 (4 -> 256), fp32 VALU, write split f16 ----------
    {
        const int l5 = lane & 31;
        const int j0 = wv * 64 + l5 * 2;
        const int ph = (lane >> 5) * 4;
        float w00[2], w01[2], w02[2], w03[2], bb[2];
        #pragma unroll
        for (int e = 0; e < 2; ++e) {
            int j = j0 + e;
            w00[e] = W0[j]; w01[e] = W0[256 + j]; w02[e] = W0[512 + j]; w03[e] = W0[768 + j];
            bb[e] = b0[j];
        }
        #pragma unroll
        for (int pp = 0; pp < 4; ++pp) {
            int p = ph + pp;
            float hx = pin[0][p];
            float hy = pin[1][p];
            float ht = 2.f * pin[2][p] - 1.f;
            float hn = 2.f * (pin[3][p] - 0.01f) * (1.f / 0.09f) - 1.f;
            float a[6][2];
            #pragma unroll
            for (int e = 0; e < 2; ++e) {
                float z  = hx * w00[e] + hy * w01[e] + ht * w02[e] + hn * w03[e] + bb[e];
                float zx = w00[e], zy = w01[e], zt = 2.f * w02[e];
                float s  = 1.f / (1.f + __expf(-z));
                float g1 = s + z * s * (1.f - s);
                float g2 = s * (1.f - s) * (2.f + z * (1.f - 2.f * s));
                a[0][e] = z * s;
                a[1][e] = g1 * zx; a[2][e] = g1 * zy; a[3][e] = g1 * zt;
                a[4][e] = g2 * zx * zx; a[5][e] = g2 * zy * zy;
            }
            #pragma unroll
            for (int c = 0; c < 6; ++c) {
                int idx = swz(c * PTS + p, j0);
                v2hf hh = pkrtz(a[c][0], a[c][1]);
                v2hf ll = pkrtz(a[c][0] - (float)hh[0], a[c][1] - (float)hh[1]);
                *(v2hf*)&Ah[idx] = hh;
                *(v2hf*)&Al[idx] = ll;
            }
        }
    }
    __syncthreads();

    // ---------------- hidden layers 1..3: split-f16 MFMA + fused activation ---
    const float* bias_ptr[3] = { b1, b2, b3 };
    for (int L = 0; L < 3; ++L) {
        const f16* __restrict__ bhL = bh + (size_t)L * NLAYER_ELEMS;
        const f16* __restrict__ blL = bl + (size_t)L * NLAYER_ELEMS;
        const float* __restrict__ bv = bias_ptr[L];

        v4f acc[4][3];     // [nTile t][mTile] ; wave owns neuron cols wv*64..+63
        #pragma unroll
        for (int t = 0; t < 4; ++t)
            #pragma unroll
            for (int mt = 0; mt < 3; ++mt)
                acc[t][mt] = (v4f){0.f, 0.f, 0.f, 0.f};

        #pragma unroll 2
        for (int ks = 0; ks < 8; ++ks) {
            const int cb = (((4 * ks + quad) ^ lnx) << 3);
            v8hf a_h[3], a_l[3];
            #pragma unroll
            for (int mt = 0; mt < 3; ++mt) {
                const int rb = (mt * 16 + ln) * 256 + cb;
                a_h[mt] = *(const v8hf*)&Ah[rb];
                a_l[mt] = *(const v8hf*)&Al[rb];
            }
            v8hf w_h[4], w_l[4];
            #pragma unroll
            for (int t = 0; t < 4; ++t) {
                int n = wv * 64 + t * 16 + ln;
                size_t o = (size_t)(ks * 256 + n) * 32 + quad * 8;
                w_h[t] = *(const v8hf*)(bhL + o);
                w_l[t] = *(const v8hf*)(blL + o);
            }
            #pragma unroll
            for (int t = 0; t < 4; ++t)
                #pragma unroll
                for (int mt = 0; mt < 3; ++mt) {
                    acc[t][mt] = __builtin_amdgcn_mfma_f32_16x16x32_f16(w_h[t], a_h[mt], acc[t][mt], 0, 0, 0);
                    acc[t][mt] = __builtin_amdgcn_mfma_f32_16x16x32_f16(w_h[t], a_l[mt], acc[t][mt], 0, 0, 0);
                    acc[t][mt] = __builtin_amdgcn_mfma_f32_16x16x32_f16(w_l[t], a_h[mt], acc[t][mt], 0, 0, 0);
                }
        }
        __syncthreads();   // all reads of A done before overwrite

        // Fused epilogue + activation, all in registers.
        // Lane pair (ln, ln+8): A-lane (ln<8) holds {c0=z, c2=zy, c4=zxx} of p=ln;
        // B-lane holds {c1=zx, c3=zt, c5=zyy} of p=ln-8.
        const bool isA = (ln < 8);
        #pragma unroll
        for (int t = 0; t < 4; ++t) {
            const int nb = wv * 64 + t * 16 + quad * 4;
            const float4 bq = *(const float4*)(bv + nb);
            const float bsel[4] = { isA ? bq.x : 0.f, isA ? bq.y : 0.f,
                                    isA ? bq.z : 0.f, isA ? bq.w : 0.f };
            float a0v[4], a1v[4], a2v[4];
            #pragma unroll
            for (int r = 0; r < 4; ++r) {
                float accv0 = acc[t][0][r] + bsel[r];      // A: z(+bias), B: zx
                float acc1  = acc[t][1][r];                // A: zy,       B: zt
                float acc2  = acc[t][2][r];                // A: zxx,      B: zyy
                float o0 = __shfl_xor(accv0, 8);
                float o1 = __shfl_xor(acc1, 8);
                float z  = isA ? accv0 : o0;               // z for both lanes
                float sq = isA ? o0    : o1;               // A: zx, B: zy
                float s  = 1.f / (1.f + __expf(-z));
                float g1 = s + z * s * (1.f - s);
                float g2 = s * (1.f - s) * (2.f + z * (1.f - 2.f * s));
                a0v[r] = isA ? (z * s) : (g1 * accv0);     // c0 | c1
                a1v[r] = g1 * acc1;                        // c2 | c3
                a2v[r] = g2 * sq * sq + g1 * acc2;         // c4 | c5
            }
            store_split(a0v, ln,      nb, Ah, Al);
            store_split(a1v, 16 + ln, nb, Ah, Al);
            store_split(a2v, 32 + ln, nb, Ah, Al);
        }
        __syncthreads();
    }

    // ---------------- output layer (256 -> 2) + residual, fp32 VALU -----------
    #pragma unroll
    for (int d = 0; d < 24; ++d) {
        int D  = wv * 24 + d;
        int p  = D / 12;
        int rm = D % 12;
        int c  = rm >> 1;
        int o  = rm & 1;
        int m  = c * PTS + p;
        int k0 = lane * 4;
        int idx = swz(m, k0);
        v4hf hh = *(v4hf*)&Ah[idx];
        v4hf ll = *(v4hf*)&Al[idx];
        float partial = 0.f;
        #pragma unroll
        for (int i = 0; i < 4; ++i)
            partial += ((float)hh[i] + (float)ll[i]) * W4[(k0 + i) * 2 + o];
        #pragma unroll
        for (int off = 32; off > 0; off >>= 1)
            partial += __shfl_down(partial, off);
        if (lane == 0)
            red[p][rm] = partial + ((c == 0) ? b4[o] : 0.f);
    }
    __syncthreads();

    if (tid < PTS) {
        int p = tid;
        float u   = red[p][0],  v   = red[p][1];
        float ux  = red[p][2],  vx  = red[p][3];
        float uy  = red[p][4],  vy  = red[p][5];
        float ut  = red[p][6],  vt  = red[p][7];
        float uxx = red[p][8],  vxx = red[p][9];
        float uyy = red[p][10], vyy = red[p][11];
        float nuv = pin[3][p];
        float fu = ut + u * ux + v * uy - nuv * (uxx + uyy);
        float fv = vt + u * vx + v * vy - nuv * (vxx + vyy);
        out[(p0 + p) * 2 + 0] = fu;
        out[(p0 + p) * 2 + 1] = fv;
    }
}

extern "C" void kernel_launch(void* const* d_in, const int* in_sizes, int n_in,
                              void* d_out, int out_size, void* d_ws, size_t ws_size,
                              hipStream_t stream) {
    const float* x  = (const float*)d_in[0];
    const float* y  = (const float*)d_in[1];
    const float* t  = (const float*)d_in[2];
    const float* nu = (const float*)d_in[3];
    const float* W0 = (const float*)d_in[4];
    const float* b0 = (const float*)d_in[5];
    const float* W1 = (const float*)d_in[6];
    const float* b1 = (const float*)d_in[7];
    const float* W2 = (const float*)d_in[8];
    const float* b2 = (const float*)d_in[9];
    const float* W3 = (const float*)d_in[10];
    const float* b3 = (const float*)d_in[11];
    const float* W4 = (const float*)d_in[12];
    const float* b4 = (const float*)d_in[13];
    float* o = (float*)d_out;

    f16* bh = (f16*)d_ws;                          // 3*65536 f16 = 384 KB
    f16* bl = bh + 3 * (size_t)NLAYER_ELEMS;       // 384 KB more

    hipLaunchKernelGGL(pack_weights, dim3(96), dim3(256), 0, stream, W1, W2, W3, bh, bl);
    hipLaunchKernelGGL(pinn_burgers_kernel, dim3(NPTS / PTS), dim3(256), 0, stream,
                       x, y, t, nu, W0, b0, b1, b2, b3, W4, b4, bh, bl, o);
}

// Round 6
// 224.271 us; speedup vs baseline: 1.0009x; 1.0009x over previous
//
#include <hip/hip_runtime.h>

typedef _Float16 f16;
typedef _Float16 v8hf __attribute__((ext_vector_type(8)));
typedef _Float16 v4hf __attribute__((ext_vector_type(4)));
typedef _Float16 v2hf __attribute__((ext_vector_type(2)));
typedef __fp16   v2pk __attribute__((ext_vector_type(2)));
typedef float    v4f  __attribute__((ext_vector_type(4)));

#define NPTS 16384
#define PTS  16             // points per workgroup -> M = 6*PTS = 96 site-rows
#define NLAYER_ELEMS 65536  // 256*256 f16 per layer per split

__device__ __forceinline__ v2hf pkrtz(float a, float b) {
    v2pk r = __builtin_amdgcn_cvt_pkrtz(a, b);
    return __builtin_bit_cast(v2hf, r);
}

// XOR-swizzled LDS index for logical (row m, f16-col j); row stride 256 f16.
// 16B chunks; phys chunk = chunk ^ (m&7). All accesses stay inside one chunk.
__device__ __forceinline__ int swz(int m, int j) {
    return m * 256 + ((((j >> 3) ^ (m & 7)) << 3) | (j & 7));
}

// ---------------- prepass: split+transpose W1..W3 into MFMA A-operand order ----
// Bpack[L][ks][n][kk] (f16). 384 blocks x 256 thr; thread does 2 kk of one n.
__global__ void pack_weights(const float* __restrict__ W1, const float* __restrict__ W2,
                             const float* __restrict__ W3, f16* __restrict__ bh,
                             f16* __restrict__ bl) {
    const int b  = blockIdx.x;           // b = L*128 + ks*16 + q*4 + kg
    const int kg = b & 3;
    const int q  = (b >> 2) & 3;
    const int ks = (b >> 4) & 7;
    const int L  = b >> 7;
    const float* W = (L == 0) ? W1 : (L == 1) ? W2 : W3;
    const int n   = q * 64 + (threadIdx.x & 63);
    const int kk0 = kg * 8 + (threadIdx.x >> 6) * 2;
    f16 h[2], l[2];
    #pragma unroll
    for (int i = 0; i < 2; ++i) {
        float w = W[(ks * 32 + kk0 + i) * 256 + n];   // coalesced along n
        f16 hh = (f16)w;
        h[i] = hh;
        l[i] = (f16)(w - (float)hh);
    }
    size_t off = (size_t)L * NLAYER_ELEMS + (size_t)(ks * 256 + n) * 32 + kk0;
    *(v2hf*)(bh + off) = *(v2hf*)h;
    *(v2hf*)(bl + off) = *(v2hf*)l;
}

__device__ __forceinline__ void store_split(const float* a, int m, int nb,
                                            f16* __restrict__ Ah, f16* __restrict__ Al) {
    v2hf h01 = pkrtz(a[0], a[1]);
    v2hf h23 = pkrtz(a[2], a[3]);
    v2hf l01 = pkrtz(a[0] - (float)h01[0], a[1] - (float)h01[1]);
    v2hf l23 = pkrtz(a[2] - (float)h23[0], a[3] - (float)h23[1]);
    v4hf hi = { h01[0], h01[1], h23[0], h23[1] };
    v4hf lo = { l01[0], l01[1], l23[0], l23[1] };
    int idx = swz(m, nb);
    *(v4hf*)&Ah[idx] = hi;
    *(v4hf*)&Al[idx] = lo;
}

// ---------------- main kernel --------------------------------------------------
// Channels: 0=val 1=dx 2=dy 3=dt 4=dxx 5=dyy; site-row m = c*16 + p.
// M=96: m-tile mt == channel mt. 512 threads = 8 waves; wave wv owns neuron
// slice [wv*32, wv*32+32) (t=0,1). D col(ln)=point p, D row(quad*4+reg)=neuron.
// All 6 channels of point ln live in ONE lane's acc[t][0..5] -> lane-local
// activation, no shuffles.
__global__ __launch_bounds__(512, 2) void pinn_burgers_kernel(
    const float* __restrict__ gx, const float* __restrict__ gy,
    const float* __restrict__ gt, const float* __restrict__ gnu,
    const float* __restrict__ W0, const float* __restrict__ b0,
    const float* __restrict__ b1, const float* __restrict__ b2,
    const float* __restrict__ b3,
    const float* __restrict__ W4, const float* __restrict__ b4,
    const f16* __restrict__ bh, const f16* __restrict__ bl,
    float* __restrict__ out)
{
    extern __shared__ f16 smem[];
    f16* __restrict__ Ah = smem;                 // 96*256 f16 = 49152 B
    f16* __restrict__ Al = smem + 96 * 256;      // 49152 B
    float* red = (float*)(smem + 2 * 96 * 256);  // [16][12]
    float* pin = red + PTS * 12;                 // [4][16]

    const int tid  = threadIdx.x;
    const int lane = tid & 63;
    const int wv   = tid >> 6;        // 8 waves
    const int ln   = lane & 15;
    const int quad = lane >> 4;
    const int lnx  = ln & 7;
    const int p0   = blockIdx.x * PTS;

    if (tid < 4 * PTS) {
        int c = tid >> 4, p = tid & 15;
        const float* src = (c == 0) ? gx : (c == 1) ? gy : (c == 2) ? gt : gnu;
        pin[c * PTS + p] = src[p0 + p];
    }
    __syncthreads();

    // ---------------- layer 0 (4 -> 256), fp32 VALU, write split f16 ----------
    {
        const int j0 = wv * 32 + ln * 2;    // 2 neurons per lane
        const int ph = quad * 4;            // 4 points per lane
        float w00[2], w01[2], w02[2], w03[2], bb[2];
        #pragma unroll
        for (int e = 0; e < 2; ++e) {
            int j = j0 + e;
            w00[e] = W0[j]; w01[e] = W0[256 + j]; w02[e] = W0[512 + j]; w03[e] = W0[768 + j];
            bb[e] = b0[j];
        }
        #pragma unroll
        for (int pp = 0; pp < 4; ++pp) {
            int p = ph + pp;
            float hx = pin[0 * PTS + p];
            float hy = pin[1 * PTS + p];
            float ht = 2.f * pin[2 * PTS + p] - 1.f;
            float hn = 2.f * (pin[3 * PTS + p] - 0.01f) * (1.f / 0.09f) - 1.f;
            float a[6][2];
            #pragma unroll
            for (int e = 0; e < 2; ++e) {
                float z  = hx * w00[e] + hy * w01[e] + ht * w02[e] + hn * w03[e] + bb[e];
                float zx = w00[e], zy = w01[e], zt = 2.f * w02[e];
                float s  = 1.f / (1.f + __expf(-z));
                float g1 = s + z * s * (1.f - s);
                float g2 = s * (1.f - s) * (2.f + z * (1.f - 2.f * s));
                a[0][e] = z * s;
                a[1][e] = g1 * zx; a[2][e] = g1 * zy; a[3][e] = g1 * zt;
                a[4][e] = g2 * zx * zx; a[5][e] = g2 * zy * zy;
            }
            #pragma unroll
            for (int c = 0; c < 6; ++c) {
                int idx = swz(c * PTS + p, j0);
                v2hf hh = pkrtz(a[c][0], a[c][1]);
                v2hf ll = pkrtz(a[c][0] - (float)hh[0], a[c][1] - (float)hh[1]);
                *(v2hf*)&Ah[idx] = hh;
                *(v2hf*)&Al[idx] = ll;
            }
        }
    }
    __syncthreads();

    // ---------------- hidden layers 1..3: split-f16 MFMA + fused activation ---
    const float* bias_ptr[3] = { b1, b2, b3 };
    for (int L = 0; L < 3; ++L) {
        const f16* __restrict__ bhL = bh + (size_t)L * NLAYER_ELEMS;
        const f16* __restrict__ blL = bl + (size_t)L * NLAYER_ELEMS;
        const float* __restrict__ bv = bias_ptr[L];

        v4f acc[2][6];     // [nTile t][channel tile mt]
        #pragma unroll
        for (int t = 0; t < 2; ++t)
            #pragma unroll
            for (int mt = 0; mt < 6; ++mt)
                acc[t][mt] = (v4f){0.f, 0.f, 0.f, 0.f};

        #pragma unroll 2
        for (int ks = 0; ks < 8; ++ks) {
            const int cb = (((4 * ks + quad) ^ lnx) << 3);
            v8hf a_h[6], a_l[6];
            #pragma unroll
            for (int mt = 0; mt < 6; ++mt) {
                const int rb = (mt * 16 + ln) * 256 + cb;
                a_h[mt] = *(const v8hf*)&Ah[rb];
                a_l[mt] = *(const v8hf*)&Al[rb];
            }
            v8hf w_h[2], w_l[2];
            #pragma unroll
            for (int t = 0; t < 2; ++t) {
                int n = wv * 32 + t * 16 + ln;
                size_t o = (size_t)(ks * 256 + n) * 32 + quad * 8;
                w_h[t] = *(const v8hf*)(bhL + o);
                w_l[t] = *(const v8hf*)(blL + o);
            }
            #pragma unroll
            for (int t = 0; t < 2; ++t)
                #pragma unroll
                for (int mt = 0; mt < 6; ++mt) {
                    acc[t][mt] = __builtin_amdgcn_mfma_f32_16x16x32_f16(w_h[t], a_h[mt], acc[t][mt], 0, 0, 0);
                    acc[t][mt] = __builtin_amdgcn_mfma_f32_16x16x32_f16(w_h[t], a_l[mt], acc[t][mt], 0, 0, 0);
                    acc[t][mt] = __builtin_amdgcn_mfma_f32_16x16x32_f16(w_l[t], a_h[mt], acc[t][mt], 0, 0, 0);
                }
        }
        __syncthreads();   // all reads of A done before overwrite

        // Fused epilogue + activation, fully lane-local (channel == mt tile).
        #pragma unroll
        for (int t = 0; t < 2; ++t) {
            const int nb = wv * 32 + t * 16 + quad * 4;
            const float4 bq = *(const float4*)(bv + nb);
            const float bb[4] = { bq.x, bq.y, bq.z, bq.w };
            float av[6][4];
            #pragma unroll
            for (int r = 0; r < 4; ++r) {
                float z   = acc[t][0][r] + bb[r];
                float zx  = acc[t][1][r];
                float zy  = acc[t][2][r];
                float zt  = acc[t][3][r];
                float zxx = acc[t][4][r];
                float zyy = acc[t][5][r];
                float s  = 1.f / (1.f + __expf(-z));
                float g1 = s + z * s * (1.f - s);
                float g2 = s * (1.f - s) * (2.f + z * (1.f - 2.f * s));
                av[0][r] = z * s;
                av[1][r] = g1 * zx;
                av[2][r] = g1 * zy;
                av[3][r] = g1 * zt;
                av[4][r] = g2 * zx * zx + g1 * zxx;
                av[5][r] = g2 * zy * zy + g1 * zyy;
            }
            #pragma unroll
            for (int c = 0; c < 6; ++c)
                store_split(av[c], c * 16 + ln, nb, Ah, Al);
        }
        __syncthreads();
    }

    // ---------------- output layer (256 -> 2) + residual, fp32 VALU -----------
    // 192 dots (p,c,o) of length 256; each wave does 24, lanes k-strided.
    #pragma unroll
    for (int d = 0; d < 24; ++d) {
        int D  = wv * 24 + d;
        int p  = D / 12;
        int rm = D % 12;
        int c  = rm >> 1;
        int o  = rm & 1;
        int m  = c * 16 + p;
        int k0 = lane * 4;
        int idx = swz(m, k0);
        v4hf hh = *(v4hf*)&Ah[idx];
        v4hf ll = *(v4hf*)&Al[idx];
        float partial = 0.f;
        #pragma unroll
        for (int i = 0; i < 4; ++i)
            partial += ((float)hh[i] + (float)ll[i]) * W4[(k0 + i) * 2 + o];
        #pragma unroll
        for (int off = 32; off > 0; off >>= 1)
            partial += __shfl_down(partial, off);
        if (lane == 0)
            red[p * 12 + rm] = partial + ((c == 0) ? b4[o] : 0.f);
    }
    __syncthreads();

    if (tid < PTS) {
        int p = tid;
        float u   = red[p*12+0],  v   = red[p*12+1];
        float ux  = red[p*12+2],  vx  = red[p*12+3];
        float uy  = red[p*12+4],  vy  = red[p*12+5];
        float ut  = red[p*12+6],  vt  = red[p*12+7];
        float uxx = red[p*12+8],  vxx = red[p*12+9];
        float uyy = red[p*12+10], vyy = red[p*12+11];
        float nuv = pin[3 * PTS + p];
        float fu = ut + u * ux + v * uy - nuv * (uxx + uyy);
        float fv = vt + u * vx + v * vy - nuv * (vxx + vyy);
        out[(p0 + p) * 2 + 0] = fu;
        out[(p0 + p) * 2 + 1] = fv;
    }
}

extern "C" void kernel_launch(void* const* d_in, const int* in_sizes, int n_in,
                              void* d_out, int out_size, void* d_ws, size_t ws_size,
                              hipStream_t stream) {
    const float* x  = (const float*)d_in[0];
    const float* y  = (const float*)d_in[1];
    const float* t  = (const float*)d_in[2];
    const float* nu = (const float*)d_in[3];
    const float* W0 = (const float*)d_in[4];
    const float* b0 = (const float*)d_in[5];
    const float* W1 = (const float*)d_in[6];
    const float* b1 = (const float*)d_in[7];
    const float* W2 = (const float*)d_in[8];
    const float* b2 = (const float*)d_in[9];
    const float* W3 = (const float*)d_in[10];
    const float* b3 = (const float*)d_in[11];
    const float* W4 = (const float*)d_in[12];
    const float* b4 = (const float*)d_in[13];
    float* o = (float*)d_out;

    f16* bh = (f16*)d_ws;                          // 3*65536 f16 = 384 KB
    f16* bl = bh + 3 * (size_t)NLAYER_ELEMS;       // 384 KB more

    // Dynamic LDS: Ah+Al (96 KB) + red (768 B) + pin (256 B)
    const size_t shmem = 2 * 96 * 256 * sizeof(f16) + (PTS * 12 + 4 * PTS) * sizeof(float);
    static bool attr_set = false;   // idempotent host-side attribute, not a stream op
    (void)hipFuncSetAttribute((const void*)pinn_burgers_kernel,
                              hipFuncAttributeMaxDynamicSharedMemorySize, (int)shmem);

    hipLaunchKernelGGL(pack_weights, dim3(384), dim3(256), 0, stream, W1, W2, W3, bh, bl);
    hipLaunchKernelGGL(pinn_burgers_kernel, dim3(NPTS / PTS), dim3(512), shmem, stream,
                       x, y, t, nu, W0, b0, b1, b2, b3, W4, b4, bh, bl, o);
}